// Round 7
// baseline (306.421 us; speedup 1.0000x reference)
//
#include <hip/hip_runtime.h>

#define N_NODES 100000
#define N_EDGES 1600000
#define D 64
#define H 128
#define SCAN_BS 512
#define SCAN_NBLK ((N_NODES + SCAN_BS - 1) / SCAN_BS)   // 196

#define SLOT_CAP 64
#define OVF_CAP 4096

#define MFMA_GRID 512        // 2 blocks/CU
#define SH_STRIDE 132        // h-buffer row stride (words): 16B-aligned, 2-way banks

typedef __attribute__((ext_vector_type(8))) short short8;   // 8 x bf16 (4 VGPRs)
typedef __attribute__((ext_vector_type(4))) float floatx4;  // MFMA acc
typedef __attribute__((ext_vector_type(4))) unsigned short ushort4_t;

__device__ __forceinline__ unsigned short f2bf(float f) {
    unsigned u = __builtin_bit_cast(unsigned, f);
    u += 0x7FFFu + ((u >> 16) & 1u);          // round-to-nearest-even
    return (unsigned short)(u >> 16);
}
__device__ __forceinline__ float bf2f(unsigned short u) {
    unsigned v = ((unsigned)u) << 16;
    return __builtin_bit_cast(float, v);
}

// ===========================================================================
// utility
// ===========================================================================
__global__ __launch_bounds__(256) void k_zero(int* __restrict__ p, int n) {
    int i = blockIdx.x * 256 + threadIdx.x;
    if (i < n) p[i] = 0;
}

// x (fp32) -> x16 (bf16) streaming convert
__global__ __launch_bounds__(256) void k_xbf16(const float4* __restrict__ x4,
                                               ushort4_t* __restrict__ y, int n4) {
    int i = blockIdx.x * 256 + threadIdx.x;
    if (i >= n4) return;
    float4 v = x4[i];
    ushort4_t o;
    o[0] = f2bf(v.x); o[1] = f2bf(v.y); o[2] = f2bf(v.z); o[3] = f2bf(v.w);
    y[i] = o;
}

// ===========================================================================
// One-pass slotted adjacency build: slots[d*64 + p] = src, p = atomic rank.
// Overflow (deg > 64; ~impossible for this distribution) goes to ovf list.
// ===========================================================================
__global__ __launch_bounds__(256) void k_build(const int* __restrict__ src,
                                               const int* __restrict__ dst,
                                               int* __restrict__ cnt,
                                               int* __restrict__ slots,
                                               int* __restrict__ ovfn,
                                               int* __restrict__ ovf) {
    int e = blockIdx.x * 256 + threadIdx.x;
    if (e >= N_EDGES) return;
    int d = dst[e];
    int s = src[e];
    int p = atomicAdd(&cnt[d], 1);
    if (p < SLOT_CAP) {
        slots[(size_t)d * SLOT_CAP + p] = s;
    } else {
        int o = atomicAdd(ovfn, 1);
        if (o < OVF_CAP) { ovf[2 * o] = d; ovf[2 * o + 1] = s; }
    }
}

// ===========================================================================
// bf16-gather aggregation: one 64-lane wave per node, 2 edges per load.
// half = lane>>5 handles edge i+half; fp = lane&31 handles features {2fp,2fp+1}.
// Cross-half reduce via shfl_xor(32); exact fp32 + x[node] at the end.
// ===========================================================================
__global__ __launch_bounds__(256) void k_agg2(const float* __restrict__ x,
                                              const unsigned short* __restrict__ x16,
                                              const int* __restrict__ slots,
                                              const int* __restrict__ cnt,
                                              float* __restrict__ out) {
    int node = blockIdx.x * 4 + (threadIdx.x >> 6);
    if (node >= N_NODES) return;
    int l = threadIdx.x & 63;
    int half = l >> 5, fp = l & 31;
    int deg = cnt[node];
    if (deg > SLOT_CAP) deg = SLOT_CAP;
    const int* sl = slots + (size_t)node * SLOT_CAP;

    float a0 = 0.f, a1 = 0.f, b0 = 0.f, b1 = 0.f;
    int i = 0;
    for (; i + 4 <= deg; i += 4) {
        int e0 = sl[i + half], e1 = sl[i + 2 + half];
        ushort2 u0 = *(const ushort2*)&x16[(size_t)e0 * D + fp * 2];
        ushort2 u1 = *(const ushort2*)&x16[(size_t)e1 * D + fp * 2];
        a0 += bf2f(u0.x); a1 += bf2f(u0.y);
        b0 += bf2f(u1.x); b1 += bf2f(u1.y);
    }
    if (i + 2 <= deg) {
        int e0 = sl[i + half];
        ushort2 u0 = *(const ushort2*)&x16[(size_t)e0 * D + fp * 2];
        a0 += bf2f(u0.x); a1 += bf2f(u0.y);
        i += 2;
    }
    if (i < deg && half == 0) {
        int e0 = sl[i];
        ushort2 u0 = *(const ushort2*)&x16[(size_t)e0 * D + fp * 2];
        a0 += bf2f(u0.x); a1 += bf2f(u0.y);
    }
    float s0 = a0 + b0, s1 = a1 + b1;
    s0 += __shfl_xor(s0, 32);
    s1 += __shfl_xor(s1, 32);
    if (half == 0) {
        float2 xv = *(const float2*)&x[(size_t)node * D + fp * 2];
        float2 o; o.x = xv.x + s0; o.y = xv.y + s1;
        *(float2*)&out[(size_t)node * D + fp * 2] = o;
    }
}

// overflow cleanup (normally novf == 0; must be launched every call)
__global__ __launch_bounds__(256) void k_ovf(const int* __restrict__ ovfn,
                                             const int* __restrict__ ovf,
                                             const float* __restrict__ x,
                                             float* __restrict__ out) {
    int n = *ovfn;
    if (n > OVF_CAP) n = OVF_CAP;
    int f = threadIdx.x & 63;
    for (int idx = threadIdx.x >> 6; idx < n; idx += 4) {
        int d = ovf[2 * idx], s = ovf[2 * idx + 1];
        atomicAdd(&out[(size_t)d * D + f], x[(size_t)s * D + f]);
    }
}

// ===========================================================================
// Tier-B fallback (R6-proven): CSR via histpos/scan/fill2 + fp32 gather
// ===========================================================================
__global__ __launch_bounds__(256) void k_histpos(const int* __restrict__ dst,
                                                 int* __restrict__ cnt,
                                                 int* __restrict__ pos) {
    int e = blockIdx.x * 256 + threadIdx.x;
    if (e < N_EDGES) pos[e] = atomicAdd(&cnt[dst[e]], 1);
}

__global__ __launch_bounds__(SCAN_BS) void k_scan1(const int* __restrict__ cnt,
                                                   int* __restrict__ ends,
                                                   int* __restrict__ bsum) {
    __shared__ int s[SCAN_BS];
    int t = threadIdx.x, b = blockIdx.x;
    int id = b * SCAN_BS + t;
    s[t] = (id < N_NODES) ? cnt[id] : 0;
    __syncthreads();
    for (int off = 1; off < SCAN_BS; off <<= 1) {
        int u = (t >= off) ? s[t - off] : 0;
        __syncthreads();
        s[t] += u;
        __syncthreads();
    }
    if (id < N_NODES) ends[id] = s[t];
    if (t == SCAN_BS - 1) bsum[b] = s[t];
}

__global__ __launch_bounds__(256) void k_scan2(int* __restrict__ bsum) {
    __shared__ int s[256];
    int t = threadIdx.x;
    s[t] = (t < SCAN_NBLK) ? bsum[t] : 0;
    __syncthreads();
    for (int off = 1; off < 256; off <<= 1) {
        int u = (t >= off) ? s[t - off] : 0;
        __syncthreads();
        s[t] += u;
        __syncthreads();
    }
    if (t < SCAN_NBLK) bsum[t] = s[t];
}

__global__ __launch_bounds__(SCAN_BS) void k_scan3(int* __restrict__ ends,
                                                   const int* __restrict__ bsum) {
    int t = threadIdx.x, b = blockIdx.x;
    int id = b * SCAN_BS + t;
    if (b > 0 && id < N_NODES) ends[id] += bsum[b - 1];
}

__global__ __launch_bounds__(256) void k_fill2(const int* __restrict__ src,
                                               const int* __restrict__ dst,
                                               const int* __restrict__ pos,
                                               const int* __restrict__ ends,
                                               int* __restrict__ csr) {
    int e = blockIdx.x * 256 + threadIdx.x;
    if (e >= N_EDGES) return;
    int d = dst[e];
    int start = (d > 0) ? ends[d - 1] : 0;
    csr[start + pos[e]] = src[e];
}

__global__ __launch_bounds__(256) void k_agg(const float* __restrict__ x,
                                             const int* __restrict__ csr,
                                             const int* __restrict__ ends,
                                             float* __restrict__ out) {
    int node = blockIdx.x * 4 + (threadIdx.x >> 6);
    if (node >= N_NODES) return;
    int f = threadIdx.x & 63;
    int start = (node > 0) ? ends[node - 1] : 0;
    int end = ends[node];
    float a0 = x[(size_t)node * D + f], a1 = 0.f, a2 = 0.f, a3 = 0.f;
    int e = start;
    for (; e + 4 <= end; e += 4) {
        int s0 = csr[e], s1 = csr[e + 1], s2 = csr[e + 2], s3 = csr[e + 3];
        a0 += x[(size_t)s0 * D + f];
        a1 += x[(size_t)s1 * D + f];
        a2 += x[(size_t)s2 * D + f];
        a3 += x[(size_t)s3 * D + f];
    }
    for (; e < end; e++) a0 += x[(size_t)csr[e] * D + f];
    out[(size_t)node * D + f] = (a0 + a1) + (a2 + a3);
}

// ===========================================================================
// Tier-C fallback: atomic scatter (R2-proven)
// ===========================================================================
__global__ __launch_bounds__(256) void k_init(const float4* __restrict__ x4,
                                              float4* __restrict__ agg4, int n4) {
    int i = blockIdx.x * 256 + threadIdx.x;
    if (i < n4) agg4[i] = x4[i];
}

__global__ __launch_bounds__(256) void k_scatter(const float4* __restrict__ x4,
                                                 const int* __restrict__ src,
                                                 const int* __restrict__ dst,
                                                 float* __restrict__ agg) {
    int gid = blockIdx.x * 256 + threadIdx.x;
    int e = gid >> 4;
    if (e >= N_EDGES) return;
    int c = gid & 15;
    float4 v = x4[src[e] * 16 + c];
    float* p = agg + (size_t)dst[e] * D + c * 4;
    atomicAdd(p + 0, v.x);
    atomicAdd(p + 1, v.y);
    atomicAdd(p + 2, v.z);
    atomicAdd(p + 3, v.w);
}

// ===========================================================================
// MFMA bf16 fused MLP, in-place on d_out (R6-proven).
// ===========================================================================
__global__ __launch_bounds__(256) void k_mlp_mfma(float* __restrict__ io,
                                                  const float* __restrict__ W1,
                                                  const float* __restrict__ b1,
                                                  const float* __restrict__ W2,
                                                  const float* __restrict__ b2) {
    __shared__ unsigned short sW1b[8192];       // 16 KB: frag f=(kt*8+nt), idx (f*64+l)*8+j
    __shared__ unsigned short sW2b[8192];       // 16 KB: frag f=(kt*4+nt)
    __shared__ float sh[4][16 * SH_STRIDE];     // 33 KB: per-wave h buffer
    __shared__ float sb1[H];
    __shared__ float sb2[D];

    int t = threadIdx.x;

    for (int q = t; q < 8192; q += 256) {
        int j = q & 7, l = (q >> 3) & 63, f = q >> 9;
        int nt = f & 7, kt = f >> 3;
        int k = kt * 32 + ((l >> 4) << 3) + j;
        int n = nt * 16 + (l & 15);
        sW1b[q] = f2bf(W1[k * H + n]);
    }
    for (int q = t; q < 8192; q += 256) {
        int j = q & 7, l = (q >> 3) & 63, f = q >> 9;
        int nt = f & 3, kt = f >> 2;
        int k = kt * 32 + ((l >> 4) << 3) + j;
        int n = nt * 16 + (l & 15);
        sW2b[q] = f2bf(W2[k * D + n]);
    }
    if (t < H) sb1[t] = b1[t];
    if (t >= H && t < H + D) sb2[t - H] = b2[t - H];
    __syncthreads();

    int w = t >> 6, l = t & 63;
    int m = l & 15, q4 = l >> 4;
    float* shw = sh[w];

    const int NT16 = N_NODES / 16;              // 6250 tiles, exact
    const int WAVES = MFMA_GRID * 4;            // 2048
    const int ITERS = (NT16 + WAVES - 1) / WAVES;

    for (int it = 0; it < ITERS; ++it) {
        int tl = it * WAVES + blockIdx.x * 4 + w;
        bool valid = tl < NT16;
        int nbase = tl * 16;

        if (valid) {
            const float* xr = io + (size_t)(nbase + m) * D + q4 * 8;
            float4 a0 = *(const float4*)(xr);
            float4 a1 = *(const float4*)(xr + 4);
            float4 c0 = *(const float4*)(xr + 32);
            float4 c1 = *(const float4*)(xr + 36);
            short8 A0, A1;
            A0[0] = f2bf(a0.x); A0[1] = f2bf(a0.y); A0[2] = f2bf(a0.z); A0[3] = f2bf(a0.w);
            A0[4] = f2bf(a1.x); A0[5] = f2bf(a1.y); A0[6] = f2bf(a1.z); A0[7] = f2bf(a1.w);
            A1[0] = f2bf(c0.x); A1[1] = f2bf(c0.y); A1[2] = f2bf(c0.z); A1[3] = f2bf(c0.w);
            A1[4] = f2bf(c1.x); A1[5] = f2bf(c1.y); A1[6] = f2bf(c1.z); A1[7] = f2bf(c1.w);

#pragma unroll
            for (int nt = 0; nt < 8; nt++) {
                float bv = sb1[nt * 16 + m];
                floatx4 acc = {bv, bv, bv, bv};
                short8 B0 = *(const short8*)&sW1b[(0 * 8 + nt) * 512 + l * 8];
                short8 B1 = *(const short8*)&sW1b[(1 * 8 + nt) * 512 + l * 8];
                acc = __builtin_amdgcn_mfma_f32_16x16x32_bf16(A0, B0, acc, 0, 0, 0);
                acc = __builtin_amdgcn_mfma_f32_16x16x32_bf16(A1, B1, acc, 0, 0, 0);
#pragma unroll
                for (int r = 0; r < 4; r++)
                    shw[(q4 * 4 + r) * SH_STRIDE + nt * 16 + m] = fmaxf(acc[r], 0.f);
            }
        }
        __syncthreads();

        if (valid) {
            short8 Ah[4];
#pragma unroll
            for (int kt = 0; kt < 4; kt++) {
                const float* hr = &shw[m * SH_STRIDE + kt * 32 + q4 * 8];
                float4 h0 = *(const float4*)(hr);
                float4 h1 = *(const float4*)(hr + 4);
                Ah[kt][0] = f2bf(h0.x); Ah[kt][1] = f2bf(h0.y);
                Ah[kt][2] = f2bf(h0.z); Ah[kt][3] = f2bf(h0.w);
                Ah[kt][4] = f2bf(h1.x); Ah[kt][5] = f2bf(h1.y);
                Ah[kt][6] = f2bf(h1.z); Ah[kt][7] = f2bf(h1.w);
            }
#pragma unroll
            for (int nt = 0; nt < 4; nt++) {
                float bv = sb2[nt * 16 + m];
                floatx4 acc = {bv, bv, bv, bv};
#pragma unroll
                for (int kt = 0; kt < 4; kt++) {
                    short8 B = *(const short8*)&sW2b[(kt * 4 + nt) * 512 + l * 8];
                    acc = __builtin_amdgcn_mfma_f32_16x16x32_bf16(Ah[kt], B, acc, 0, 0, 0);
                }
#pragma unroll
                for (int r = 0; r < 4; r++)
                    io[(size_t)(nbase + q4 * 4 + r) * D + nt * 16 + m] = acc[r];
            }
        }
        __syncthreads();
    }
}

// ===========================================================================
extern "C" void kernel_launch(void* const* d_in, const int* in_sizes, int n_in,
                              void* d_out, int out_size, void* d_ws, size_t ws_size,
                              hipStream_t stream) {
    const float* x  = (const float*)d_in[0];
    const int* eidx = (const int*)d_in[1];   // [2, N_EDGES] int32 per harness
    const float* W1 = (const float*)d_in[2];
    const float* b1 = (const float*)d_in[3];
    const float* W2 = (const float*)d_in[4];
    const float* b2 = (const float*)d_in[5];
    float* out      = (float*)d_out;         // agg buffer, then final output

    const int* src = eidx;
    const int* dst = eidx + N_EDGES;

    int ge = (N_EDGES + 255) / 256;
    int n4 = N_NODES * D / 4;

    // Tier A: cnt[N] ovfn[4] ovf[2*OVF_CAP] slots[N*64] + x16[N*64 ushort]
    size_t need_A = (size_t)(N_NODES + 4 + 2 * OVF_CAP + (size_t)N_NODES * SLOT_CAP) * sizeof(int)
                  + (size_t)N_NODES * D * sizeof(unsigned short);   // ~38.9 MB
    // Tier B: cnt[N] ends[N] bsum[512] pos[E] csr[E]
    size_t need_B = (size_t)(2 * N_NODES + 512 + 2 * N_EDGES) * sizeof(int);  // ~13.6 MB

    if (ws_size >= need_A) {
        int* cnt   = (int*)d_ws;
        int* ovfn  = cnt + N_NODES;
        int* ovf   = ovfn + 4;
        int* slots = ovf + 2 * OVF_CAP;
        unsigned short* x16 = (unsigned short*)(slots + (size_t)N_NODES * SLOT_CAP);

        k_zero<<<(N_NODES + 4 + 255) / 256, 256, 0, stream>>>(cnt, N_NODES + 4);
        k_xbf16<<<(n4 + 255) / 256, 256, 0, stream>>>((const float4*)x, (ushort4_t*)x16, n4);
        k_build<<<ge, 256, 0, stream>>>(src, dst, cnt, slots, ovfn, ovf);
        k_agg2<<<(N_NODES + 3) / 4, 256, 0, stream>>>(x, x16, slots, cnt, out);
        k_ovf<<<1, 256, 0, stream>>>(ovfn, ovf, x, out);
    } else if (ws_size >= need_B) {
        int* cnt  = (int*)d_ws;
        int* ends = cnt + N_NODES;
        int* bsum = ends + N_NODES;
        int* pos  = bsum + 512;
        int* csr  = pos + N_EDGES;

        k_zero<<<(N_NODES + 255) / 256, 256, 0, stream>>>(cnt, N_NODES);
        k_histpos<<<ge, 256, 0, stream>>>(dst, cnt, pos);
        k_scan1<<<SCAN_NBLK, SCAN_BS, 0, stream>>>(cnt, ends, bsum);
        k_scan2<<<1, 256, 0, stream>>>(bsum);
        k_scan3<<<SCAN_NBLK, SCAN_BS, 0, stream>>>(ends, bsum);
        k_fill2<<<ge, 256, 0, stream>>>(src, dst, pos, ends, csr);
        k_agg<<<(N_NODES + 3) / 4, 256, 0, stream>>>(x, csr, ends, out);
    } else {
        k_init<<<(n4 + 255) / 256, 256, 0, stream>>>((const float4*)x, (float4*)out, n4);
        long long total = (long long)N_EDGES * 16;
        k_scatter<<<(int)((total + 255) / 256), 256, 0, stream>>>(
            (const float4*)x, src, dst, out);
    }

    k_mlp_mfma<<<MFMA_GRID, 256, 0, stream>>>(out, W1, b1, W2, b2);
}

// Round 8
// 271.165 us; speedup vs baseline: 1.1300x; 1.1300x over previous
//
#include <hip/hip_runtime.h>

#define N_NODES 100000
#define N_EDGES 1600000
#define D 64
#define H 128
#define SCAN_BS 512
#define SCAN_NBLK ((N_NODES + SCAN_BS - 1) / SCAN_BS)   // 196

#define MFMA_GRID 512        // 2 blocks/CU
#define SH_STRIDE 132        // h-buffer row stride (words): 16B-aligned, 2-way banks

typedef __attribute__((ext_vector_type(8))) short short8;   // 8 x bf16 (4 VGPRs)
typedef __attribute__((ext_vector_type(4))) float floatx4;  // MFMA acc
typedef __attribute__((ext_vector_type(4))) unsigned short ushort4_t;

__device__ __forceinline__ unsigned short f2bf(float f) {
    unsigned u = __builtin_bit_cast(unsigned, f);
    u += 0x7FFFu + ((u >> 16) & 1u);          // round-to-nearest-even
    return (unsigned short)(u >> 16);
}
__device__ __forceinline__ float bf2f(unsigned short u) {
    unsigned v = ((unsigned)u) << 16;
    return __builtin_bit_cast(float, v);
}

// ===========================================================================
// utility
// ===========================================================================
__global__ __launch_bounds__(256) void k_zero(int* __restrict__ p, int n) {
    int i = blockIdx.x * 256 + threadIdx.x;
    if (i < n) p[i] = 0;
}

// x (fp32) -> x16 (bf16) streaming convert
__global__ __launch_bounds__(256) void k_xbf16(const float4* __restrict__ x4,
                                               ushort4_t* __restrict__ y, int n4) {
    int i = blockIdx.x * 256 + threadIdx.x;
    if (i >= n4) return;
    float4 v = x4[i];
    ushort4_t o;
    o[0] = f2bf(v.x); o[1] = f2bf(v.y); o[2] = f2bf(v.z); o[3] = f2bf(v.w);
    y[i] = o;
}

// ===========================================================================
// CSR build (R4/R6-proven): histpos (atomic off store path) -> scan -> fill2
// ===========================================================================
__global__ __launch_bounds__(256) void k_histpos(const int* __restrict__ dst,
                                                 int* __restrict__ cnt,
                                                 int* __restrict__ pos) {
    int e = blockIdx.x * 256 + threadIdx.x;
    if (e < N_EDGES) pos[e] = atomicAdd(&cnt[dst[e]], 1);
}

__global__ __launch_bounds__(SCAN_BS) void k_scan1(const int* __restrict__ cnt,
                                                   int* __restrict__ ends,
                                                   int* __restrict__ bsum) {
    __shared__ int s[SCAN_BS];
    int t = threadIdx.x, b = blockIdx.x;
    int id = b * SCAN_BS + t;
    s[t] = (id < N_NODES) ? cnt[id] : 0;
    __syncthreads();
    for (int off = 1; off < SCAN_BS; off <<= 1) {
        int u = (t >= off) ? s[t - off] : 0;
        __syncthreads();
        s[t] += u;
        __syncthreads();
    }
    if (id < N_NODES) ends[id] = s[t];
    if (t == SCAN_BS - 1) bsum[b] = s[t];
}

__global__ __launch_bounds__(256) void k_scan2(int* __restrict__ bsum) {
    __shared__ int s[256];
    int t = threadIdx.x;
    s[t] = (t < SCAN_NBLK) ? bsum[t] : 0;
    __syncthreads();
    for (int off = 1; off < 256; off <<= 1) {
        int u = (t >= off) ? s[t - off] : 0;
        __syncthreads();
        s[t] += u;
        __syncthreads();
    }
    if (t < SCAN_NBLK) bsum[t] = s[t];
}

__global__ __launch_bounds__(SCAN_BS) void k_scan3(int* __restrict__ ends,
                                                   const int* __restrict__ bsum) {
    int t = threadIdx.x, b = blockIdx.x;
    int id = b * SCAN_BS + t;
    if (b > 0 && id < N_NODES) ends[id] += bsum[b - 1];
}

__global__ __launch_bounds__(256) void k_fill2(const int* __restrict__ src,
                                               const int* __restrict__ dst,
                                               const int* __restrict__ pos,
                                               const int* __restrict__ ends,
                                               int* __restrict__ csr) {
    int e = blockIdx.x * 256 + threadIdx.x;
    if (e >= N_EDGES) return;
    int d = dst[e];
    int start = (d > 0) ? ends[d - 1] : 0;
    csr[start + pos[e]] = src[e];
}

// ===========================================================================
// bf16-gather aggregation over CSR: one 64-lane wave per node, 2 edges/iter.
// half = lane>>5 handles edge i+half; fp = lane&31 handles features {2fp,2fp+1}.
// Cross-half reduce via shfl_xor(32); exact fp32 + x[node] at the end.
// ===========================================================================
__global__ __launch_bounds__(256) void k_agg2(const float* __restrict__ x,
                                              const unsigned short* __restrict__ x16,
                                              const int* __restrict__ csr,
                                              const int* __restrict__ ends,
                                              float* __restrict__ out) {
    int node = blockIdx.x * 4 + (threadIdx.x >> 6);
    if (node >= N_NODES) return;
    int l = threadIdx.x & 63;
    int half = l >> 5, fp = l & 31;
    int start = (node > 0) ? ends[node - 1] : 0;
    int deg = ends[node] - start;
    const int* sl = csr + start;

    float a0 = 0.f, a1 = 0.f, b0 = 0.f, b1 = 0.f;
    int i = 0;
    for (; i + 4 <= deg; i += 4) {
        int e0 = sl[i + half], e1 = sl[i + 2 + half];
        ushort2 u0 = *(const ushort2*)&x16[(size_t)e0 * D + fp * 2];
        ushort2 u1 = *(const ushort2*)&x16[(size_t)e1 * D + fp * 2];
        a0 += bf2f(u0.x); a1 += bf2f(u0.y);
        b0 += bf2f(u1.x); b1 += bf2f(u1.y);
    }
    if (i + 2 <= deg) {
        int e0 = sl[i + half];
        ushort2 u0 = *(const ushort2*)&x16[(size_t)e0 * D + fp * 2];
        a0 += bf2f(u0.x); a1 += bf2f(u0.y);
        i += 2;
    }
    if (i < deg && half == 0) {
        int e0 = sl[i];
        ushort2 u0 = *(const ushort2*)&x16[(size_t)e0 * D + fp * 2];
        a0 += bf2f(u0.x); a1 += bf2f(u0.y);
    }
    float s0 = a0 + b0, s1 = a1 + b1;
    s0 += __shfl_xor(s0, 32);
    s1 += __shfl_xor(s1, 32);
    if (half == 0) {
        float2 xv = *(const float2*)&x[(size_t)node * D + fp * 2];
        float2 o; o.x = xv.x + s0; o.y = xv.y + s1;
        *(float2*)&out[(size_t)node * D + fp * 2] = o;
    }
}

// fp32 gather (Tier-B, R6-proven)
__global__ __launch_bounds__(256) void k_agg(const float* __restrict__ x,
                                             const int* __restrict__ csr,
                                             const int* __restrict__ ends,
                                             float* __restrict__ out) {
    int node = blockIdx.x * 4 + (threadIdx.x >> 6);
    if (node >= N_NODES) return;
    int f = threadIdx.x & 63;
    int start = (node > 0) ? ends[node - 1] : 0;
    int end = ends[node];
    float a0 = x[(size_t)node * D + f], a1 = 0.f, a2 = 0.f, a3 = 0.f;
    int e = start;
    for (; e + 4 <= end; e += 4) {
        int s0 = csr[e], s1 = csr[e + 1], s2 = csr[e + 2], s3 = csr[e + 3];
        a0 += x[(size_t)s0 * D + f];
        a1 += x[(size_t)s1 * D + f];
        a2 += x[(size_t)s2 * D + f];
        a3 += x[(size_t)s3 * D + f];
    }
    for (; e < end; e++) a0 += x[(size_t)csr[e] * D + f];
    out[(size_t)node * D + f] = (a0 + a1) + (a2 + a3);
}

// ===========================================================================
// Tier-C fallback: atomic scatter (R2-proven)
// ===========================================================================
__global__ __launch_bounds__(256) void k_init(const float4* __restrict__ x4,
                                              float4* __restrict__ agg4, int n4) {
    int i = blockIdx.x * 256 + threadIdx.x;
    if (i < n4) agg4[i] = x4[i];
}

__global__ __launch_bounds__(256) void k_scatter(const float4* __restrict__ x4,
                                                 const int* __restrict__ src,
                                                 const int* __restrict__ dst,
                                                 float* __restrict__ agg) {
    int gid = blockIdx.x * 256 + threadIdx.x;
    int e = gid >> 4;
    if (e >= N_EDGES) return;
    int c = gid & 15;
    float4 v = x4[src[e] * 16 + c];
    float* p = agg + (size_t)dst[e] * D + c * 4;
    atomicAdd(p + 0, v.x);
    atomicAdd(p + 1, v.y);
    atomicAdd(p + 2, v.z);
    atomicAdd(p + 3, v.w);
}

// ===========================================================================
// MFMA bf16 fused MLP, in-place on d_out (R6-proven).
// ===========================================================================
__global__ __launch_bounds__(256) void k_mlp_mfma(float* __restrict__ io,
                                                  const float* __restrict__ W1,
                                                  const float* __restrict__ b1,
                                                  const float* __restrict__ W2,
                                                  const float* __restrict__ b2) {
    __shared__ unsigned short sW1b[8192];       // 16 KB: frag f=(kt*8+nt), idx (f*64+l)*8+j
    __shared__ unsigned short sW2b[8192];       // 16 KB: frag f=(kt*4+nt)
    __shared__ float sh[4][16 * SH_STRIDE];     // 33 KB: per-wave h buffer
    __shared__ float sb1[H];
    __shared__ float sb2[D];

    int t = threadIdx.x;

    for (int q = t; q < 8192; q += 256) {
        int j = q & 7, l = (q >> 3) & 63, f = q >> 9;
        int nt = f & 7, kt = f >> 3;
        int k = kt * 32 + ((l >> 4) << 3) + j;
        int n = nt * 16 + (l & 15);
        sW1b[q] = f2bf(W1[k * H + n]);
    }
    for (int q = t; q < 8192; q += 256) {
        int j = q & 7, l = (q >> 3) & 63, f = q >> 9;
        int nt = f & 3, kt = f >> 2;
        int k = kt * 32 + ((l >> 4) << 3) + j;
        int n = nt * 16 + (l & 15);
        sW2b[q] = f2bf(W2[k * D + n]);
    }
    if (t < H) sb1[t] = b1[t];
    if (t >= H && t < H + D) sb2[t - H] = b2[t - H];
    __syncthreads();

    int w = t >> 6, l = t & 63;
    int m = l & 15, q4 = l >> 4;
    float* shw = sh[w];

    const int NT16 = N_NODES / 16;              // 6250 tiles, exact
    const int WAVES = MFMA_GRID * 4;            // 2048
    const int ITERS = (NT16 + WAVES - 1) / WAVES;

    for (int it = 0; it < ITERS; ++it) {
        int tl = it * WAVES + blockIdx.x * 4 + w;
        bool valid = tl < NT16;
        int nbase = tl * 16;

        if (valid) {
            const float* xr = io + (size_t)(nbase + m) * D + q4 * 8;
            float4 a0 = *(const float4*)(xr);
            float4 a1 = *(const float4*)(xr + 4);
            float4 c0 = *(const float4*)(xr + 32);
            float4 c1 = *(const float4*)(xr + 36);
            short8 A0, A1;
            A0[0] = f2bf(a0.x); A0[1] = f2bf(a0.y); A0[2] = f2bf(a0.z); A0[3] = f2bf(a0.w);
            A0[4] = f2bf(a1.x); A0[5] = f2bf(a1.y); A0[6] = f2bf(a1.z); A0[7] = f2bf(a1.w);
            A1[0] = f2bf(c0.x); A1[1] = f2bf(c0.y); A1[2] = f2bf(c0.z); A1[3] = f2bf(c0.w);
            A1[4] = f2bf(c1.x); A1[5] = f2bf(c1.y); A1[6] = f2bf(c1.z); A1[7] = f2bf(c1.w);

#pragma unroll
            for (int nt = 0; nt < 8; nt++) {
                float bv = sb1[nt * 16 + m];
                floatx4 acc = {bv, bv, bv, bv};
                short8 B0 = *(const short8*)&sW1b[(0 * 8 + nt) * 512 + l * 8];
                short8 B1 = *(const short8*)&sW1b[(1 * 8 + nt) * 512 + l * 8];
                acc = __builtin_amdgcn_mfma_f32_16x16x32_bf16(A0, B0, acc, 0, 0, 0);
                acc = __builtin_amdgcn_mfma_f32_16x16x32_bf16(A1, B1, acc, 0, 0, 0);
#pragma unroll
                for (int r = 0; r < 4; r++)
                    shw[(q4 * 4 + r) * SH_STRIDE + nt * 16 + m] = fmaxf(acc[r], 0.f);
            }
        }
        __syncthreads();

        if (valid) {
            short8 Ah[4];
#pragma unroll
            for (int kt = 0; kt < 4; kt++) {
                const float* hr = &shw[m * SH_STRIDE + kt * 32 + q4 * 8];
                float4 h0 = *(const float4*)(hr);
                float4 h1 = *(const float4*)(hr + 4);
                Ah[kt][0] = f2bf(h0.x); Ah[kt][1] = f2bf(h0.y);
                Ah[kt][2] = f2bf(h0.z); Ah[kt][3] = f2bf(h0.w);
                Ah[kt][4] = f2bf(h1.x); Ah[kt][5] = f2bf(h1.y);
                Ah[kt][6] = f2bf(h1.z); Ah[kt][7] = f2bf(h1.w);
            }
#pragma unroll
            for (int nt = 0; nt < 4; nt++) {
                float bv = sb2[nt * 16 + m];
                floatx4 acc = {bv, bv, bv, bv};
#pragma unroll
                for (int kt = 0; kt < 4; kt++) {
                    short8 B = *(const short8*)&sW2b[(kt * 4 + nt) * 512 + l * 8];
                    acc = __builtin_amdgcn_mfma_f32_16x16x32_bf16(Ah[kt], B, acc, 0, 0, 0);
                }
#pragma unroll
                for (int r = 0; r < 4; r++)
                    io[(size_t)(nbase + q4 * 4 + r) * D + nt * 16 + m] = acc[r];
            }
        }
        __syncthreads();
    }
}

// ===========================================================================
extern "C" void kernel_launch(void* const* d_in, const int* in_sizes, int n_in,
                              void* d_out, int out_size, void* d_ws, size_t ws_size,
                              hipStream_t stream) {
    const float* x  = (const float*)d_in[0];
    const int* eidx = (const int*)d_in[1];   // [2, N_EDGES] int32 per harness
    const float* W1 = (const float*)d_in[2];
    const float* b1 = (const float*)d_in[3];
    const float* W2 = (const float*)d_in[4];
    const float* b2 = (const float*)d_in[5];
    float* out      = (float*)d_out;         // agg buffer, then final output

    const int* src = eidx;
    const int* dst = eidx + N_EDGES;

    int ge = (N_EDGES + 255) / 256;
    int n4 = N_NODES * D / 4;

    // Tier A: cnt[N] ends[N] bsum[512] pos[E] csr[E] + x16[N*D] bf16 (~26.5 MB)
    size_t need_A = (size_t)(2 * N_NODES + 512 + 2 * N_EDGES) * sizeof(int)
                  + (size_t)N_NODES * D * sizeof(unsigned short);
    // Tier B: cnt[N] ends[N] bsum[512] pos[E] csr[E] (~13.6 MB)
    size_t need_B = (size_t)(2 * N_NODES + 512 + 2 * N_EDGES) * sizeof(int);

    if (ws_size >= need_A) {
        int* cnt  = (int*)d_ws;
        int* ends = cnt + N_NODES;
        int* bsum = ends + N_NODES;
        int* pos  = bsum + 512;
        int* csr  = pos + N_EDGES;
        unsigned short* x16 = (unsigned short*)(csr + N_EDGES);

        k_zero<<<(N_NODES + 255) / 256, 256, 0, stream>>>(cnt, N_NODES);
        k_xbf16<<<(n4 + 255) / 256, 256, 0, stream>>>((const float4*)x, (ushort4_t*)x16, n4);
        k_histpos<<<ge, 256, 0, stream>>>(dst, cnt, pos);
        k_scan1<<<SCAN_NBLK, SCAN_BS, 0, stream>>>(cnt, ends, bsum);
        k_scan2<<<1, 256, 0, stream>>>(bsum);
        k_scan3<<<SCAN_NBLK, SCAN_BS, 0, stream>>>(ends, bsum);
        k_fill2<<<ge, 256, 0, stream>>>(src, dst, pos, ends, csr);
        k_agg2<<<(N_NODES + 3) / 4, 256, 0, stream>>>(x, x16, csr, ends, out);
    } else if (ws_size >= need_B) {
        int* cnt  = (int*)d_ws;
        int* ends = cnt + N_NODES;
        int* bsum = ends + N_NODES;
        int* pos  = bsum + 512;
        int* csr  = pos + N_EDGES;

        k_zero<<<(N_NODES + 255) / 256, 256, 0, stream>>>(cnt, N_NODES);
        k_histpos<<<ge, 256, 0, stream>>>(dst, cnt, pos);
        k_scan1<<<SCAN_NBLK, SCAN_BS, 0, stream>>>(cnt, ends, bsum);
        k_scan2<<<1, 256, 0, stream>>>(bsum);
        k_scan3<<<SCAN_NBLK, SCAN_BS, 0, stream>>>(ends, bsum);
        k_fill2<<<ge, 256, 0, stream>>>(src, dst, pos, ends, csr);
        k_agg<<<(N_NODES + 3) / 4, 256, 0, stream>>>(x, csr, ends, out);
    } else {
        k_init<<<(n4 + 255) / 256, 256, 0, stream>>>((const float4*)x, (float4*)out, n4);
        long long total = (long long)N_EDGES * 16;
        k_scatter<<<(int)((total + 255) / 256), 256, 0, stream>>>(
            (const float4*)x, src, dst, out);
    }

    k_mlp_mfma<<<MFMA_GRID, 256, 0, stream>>>(out, W1, b1, W2, b2);
}